// Round 1
// baseline (976.568 us; speedup 1.0000x reference)
//
#include <hip/hip_runtime.h>
#include <math.h>

#define LOG_2PI_F 1.8378770664093453f

// Kernel 1: per-block partial sums of (o-x)^2 with float4 vector loads.
// 2048 blocks x 256 threads: 8 blocks/CU on 256 CUs, grid-stride loop.
__global__ void __launch_bounds__(256)
sqdiff_partial(const float4* __restrict__ o4, const float4* __restrict__ x4,
               long long n4, long long n_total, const float* __restrict__ o_s,
               const float* __restrict__ x_s, float* __restrict__ partials) {
    long long idx = (long long)blockIdx.x * blockDim.x + threadIdx.x;
    long long stride = (long long)gridDim.x * blockDim.x;
    float acc = 0.f;
    for (long long i = idx; i < n4; i += stride) {
        float4 a = o4[i];
        float4 b = x4[i];
        float d0 = a.x - b.x;
        float d1 = a.y - b.y;
        float d2 = a.z - b.z;
        float d3 = a.w - b.w;
        acc += d0 * d0 + d1 * d1 + d2 * d2 + d3 * d3;
    }
    // scalar tail (n_total not divisible by 4) -- handled by first thread only
    if (idx == 0) {
        for (long long i = n4 * 4; i < n_total; ++i) {
            float d = o_s[i] - x_s[i];
            acc += d * d;
        }
    }
    // wave-64 reduction
    #pragma unroll
    for (int off = 32; off > 0; off >>= 1)
        acc += __shfl_down(acc, off, 64);
    __shared__ float lds[4];
    int wave = threadIdx.x >> 6;
    int lane = threadIdx.x & 63;
    if (lane == 0) lds[wave] = acc;
    __syncthreads();
    if (threadIdx.x == 0) {
        float s = lds[0] + lds[1] + lds[2] + lds[3];
        partials[blockIdx.x] = s;
    }
}

// Kernel 2: reduce the block partials and apply the log-likelihood epilogue.
__global__ void __launch_bounds__(256)
finalize(const float* __restrict__ partials, int np,
         const float* __restrict__ noise_p, float* __restrict__ out,
         float nd) {
    float acc = 0.f;
    for (int i = threadIdx.x; i < np; i += blockDim.x) acc += partials[i];
    #pragma unroll
    for (int off = 32; off > 0; off >>= 1)
        acc += __shfl_down(acc, off, 64);
    __shared__ float lds[4];
    int wave = threadIdx.x >> 6;
    int lane = threadIdx.x & 63;
    if (lane == 0) lds[wave] = acc;
    __syncthreads();
    if (threadIdx.x == 0) {
        float sq = lds[0] + lds[1] + lds[2] + lds[3];
        float noise = noise_p[0];
        out[0] = -0.5f * nd * LOG_2PI_F
               - 0.5f * nd * noise
               - 0.5f * expf(-2.f * noise) * sq;
    }
}

extern "C" void kernel_launch(void* const* d_in, const int* in_sizes, int n_in,
                              void* d_out, int out_size, void* d_ws, size_t ws_size,
                              hipStream_t stream) {
    const float* o = (const float*)d_in[0];
    const float* x = (const float*)d_in[1];
    const float* noise = (const float*)d_in[2];
    float* out = (float*)d_out;
    float* partials = (float*)d_ws;

    long long n = (long long)in_sizes[0];  // total elements = n_rows * d
    long long n4 = n >> 2;

    const int BLOCKS = 2048;   // 8 blocks/CU
    const int THREADS = 256;

    sqdiff_partial<<<BLOCKS, THREADS, 0, stream>>>(
        (const float4*)o, (const float4*)x, n4, n, o, x, partials);
    finalize<<<1, THREADS, 0, stream>>>(partials, BLOCKS, noise, out, (float)n);
}